// Round 9
// baseline (134.309 us; speedup 1.0000x reference)
//
#include <hip/hip_runtime.h>

#define B_    16
#define CIN_  128
#define COUT_ 256
#define H_    56
#define W_    56
#define YP    58
#define XP    64

typedef int   i32x4 __attribute__((ext_vector_type(4)));
typedef float f4    __attribute__((ext_vector_type(4)));

// async global->LDS, 16B per lane; LDS dest wave-uniform base, lane l lands
// at base + l*16.
__device__ __forceinline__ void gload16(const void* g, void* l) {
    __builtin_amdgcn_global_load_lds(
        (const __attribute__((address_space(1))) unsigned int*)g,
        (__attribute__((address_space(3))) unsigned int*)l,
        16, 0, 0);
}

// ---------------------------------------------------------------------------
// Fused prep kernel, block-range partitioned:
//   [0,928)      : quantize x -> xqU i8 (u = xq/2-128, pad = -128) + s_pad
//   [928,1216)   : pack weights -> i8 frag-stream [i(18)][cb(2)][mh(2)][mi(4)][lane(64)][16]
//   [1216,1232)  : Wsum[cout] = sum over cin,ky,kx of weight
__global__ __launch_bounds__(256) void k_prep(
    const float* __restrict__ x, const float* __restrict__ w,
    const float* __restrict__ p_act_s, const float* __restrict__ p_act_q,
    const float* __restrict__ p_azp,  const float* __restrict__ p_guard_a,
    signed char* __restrict__ xqU, signed char* __restrict__ wt,
    float* __restrict__ s_pad, float* __restrict__ Wsum)
{
    int t = threadIdx.x;
    int blk = blockIdx.x;

    if (blk < 928) {
        // ---- quantize one (b, padded-y) row ----
        int b = blk / YP, y = blk - b * YP;
        __shared__ signed char shq[W_ * 144];   // [w][cin], stride 144 (16-mult)
        signed char* orow = xqU + (size_t)blk * XP * CIN_;

        if (y == 0 || y == YP - 1) {
            i32x4 pv = {(int)0x80808080, (int)0x80808080,
                        (int)0x80808080, (int)0x80808080};
            *(i32x4*)(orow + t * 32)      = pv;
            *(i32x4*)(orow + t * 32 + 16) = pv;
            if (t < XP) s_pad[(size_t)blk * XP + t] = 0.0f;
            return;
        }
        int h = y - 1;
        float act_s = p_act_s[0], act_q = p_act_q[0];
        float azp = p_azp[0], ga = p_guard_a[0];
        float zp = azp * act_s / ga;
        float hi = zp + act_q - act_s;
        float inv_s = 1.0f / act_s;            // act_s = 2^-4: exact

        // vectorized: 1792 float4s (56 = 14*4 exact), 16B-aligned rows
        for (int i = 0; i < 7; ++i) {
            int e = i * 256 + t;               // < 1792
            int cin = e / 14;
            int w4 = (e - cin * 14) * 4;
            f4 v = *(const f4*)(x + (((size_t)b * CIN_ + cin) * H_ + h) * W_ + w4);
            #pragma unroll
            for (int j = 0; j < 4; ++j) {
                float vv = fminf(fmaxf(v[j], zp), hi);
                float r = rintf((vv - zp) * inv_s);        // [0,255] integer
                float uq = rintf(ga * r * 0.5f) - 128.0f;  // = r-128 (ga==2)
                shq[(w4 + j) * 144 + cin] = (signed char)(int)uq;
            }
        }
        __syncthreads();
        // write padded row (16B stores, cin contiguous) + channel-sum
        #pragma unroll
        for (int i = 0; i < 2; ++i) {
            int T = i * 256 + t;               // < 512
            int xx = T >> 3;                   // 0..63
            int c16 = T & 7;
            union { i32x4 v; signed char c[16]; } u;
            if (xx >= 1 && xx <= W_) {
                u.v = *(const i32x4*)(shq + (xx - 1) * 144 + c16 * 16);
            } else {
                u.v = (i32x4){(int)0x80808080, (int)0x80808080,
                              (int)0x80808080, (int)0x80808080};
            }
            *(i32x4*)(orow + (size_t)xx * CIN_ + c16 * 16) = u.v;
            int sum = 0;
            #pragma unroll
            for (int j = 0; j < 16; ++j) sum += (int)u.c[j];
            sum += __shfl_xor(sum, 1);
            sum += __shfl_xor(sum, 2);
            sum += __shfl_xor(sum, 4);
            // sum(xq) = 2*sum(u) + 256*128; pads give exactly 0
            if (c16 == 0)
                s_pad[(size_t)blk * XP + xx] = (float)(2 * sum + 32768);
        }
        return;
    }

    if (blk < 1216) {
        // ---- weight pack into MFMA fragment stream ----
        int o = ((blk - 928) * 256 + t) * 4;   // < 294912
        int i_  = o >> 14;                     // 0..17  (= cc*9 + g)
        int cc  = (i_ >= 9) ? 1 : 0;
        int g   = i_ - cc * 9;
        int cbp = (o >> 13) & 1;
        int mh  = (o >> 12) & 1;
        int mi  = (o >> 10) & 3;
        int ln  = (o >> 4) & 63;
        int cout = cbp * 128 + mh * 64 + mi * 16 + (ln & 15);
        int cin0 = cc * 64 + (ln >> 4) * 16 + (o & 15);
        int dy = g / 3, dx = g - dy * 3;
        const float* src = w + (size_t)cout * 1152 + cin0 * 9 + dy * 3 + dx;
        union { int v; signed char c[4]; } pk;
        #pragma unroll
        for (int j = 0; j < 4; ++j)
            pk.c[j] = (signed char)(int)src[j * 9];
        *(int*)(wt + o) = pk.v;
        return;
    }

    {
        // ---- Wsum: 16 couts per block, 16 lanes per cout ----
        int bw = blk - 1216;
        int cout = bw * 16 + (t >> 4);
        int part = t & 15;
        const float* base = w + (size_t)cout * 1152 + part * 72;
        float s = 0.f;
        for (int j = 0; j < 72; ++j) s += base[j];
        s += __shfl_xor(s, 1);
        s += __shfl_xor(s, 2);
        s += __shfl_xor(s, 4);
        s += __shfl_xor(s, 8);
        if (part == 0) Wsum[cout] = s;
        return;
    }
}

// ---------------------------------------------------------------------------
// i8 implicit-GEMM, TWO pixel tiles per block sharing the A (weight) stream
// (r8, -7us), + this round: 1 BLOCK/CU VIA LDS PAD (~83 KB > 80 KB).
//   With 448 blocks all co-resident (2/CU), the kernel ran as one chip-wide
//   convoy: synchronized stage burst (3.4us, CUs idle), shared-pipe K-loop,
//   and an exposed 51 MB store tail (~8us). Forcing 1 block/CU gives 1.75
//   staggered generations: gen-2 stages/computes while gen-1 drains stores,
//   and each block's K-loop owns its SIMD's MFMA pipe exclusively
//   (32 independent MFMAs/iter keep it ~85% fed at 1 wave/SIMD).
__global__ __launch_bounds__(256, 1) void k_gemm(
    const signed char* __restrict__ xqU,  // [B][58][64][128] i8
    const signed char* __restrict__ wt,   // [18][2][2][4][64][16] i8
    const float* __restrict__ s_pad,      // [B*58][64]
    const float* __restrict__ Wsum,       // [256]
    const float* __restrict__ wzp,        // [256]
    const float* __restrict__ fps,        // [256]
    const float* __restrict__ bias,       // [256][56][56]
    const float* __restrict__ p_gw,       // guard_w
    float* __restrict__ out)              // [B][256][56][56]
{
    // [cc(2)][row(6)][x(64)][chunk(4)x16B] + 128 B guard
    __shared__ __align__(16) signed char Bh[2 * 6 * 4096 + 128];
    __shared__ __align__(16) float c2s[4 * 56];
    // occupancy limiter: total LDS ~83 KB -> exactly 1 block/CU (160 KB pool).
    // Guarded dynamic write prevents DCE of the allocation.
    __shared__ float ldspad[8192];

    int tid = threadIdx.x;
    if ((int)blockIdx.x == -1) ldspad[tid] = 1.0f;   // never taken

    int wv = tid >> 6, lane = tid & 63;
    int xl = lane & 15, q = lane >> 4;
    // XCD-bijective: 448 = 8*56; each XCD gets 56 consecutive u
    // (28 pixel groups x 2 cb, cb pairs adjacent in time).
    int bid = blockIdx.x;
    int u = (bid & 7) * 56 + (bid >> 3);
    int cb = u & 1;
    int g4 = u >> 1;                       // 0..223
    int b = g4 / 14, hp4 = g4 - b * 14;
    int H0 = hp4 * 4;                      // first of 4 output rows
    int mh = wv >> 1;                      // cout half within cb (0/1)
    int rn = wv & 1;                       // row within tile (0/1)

    // c2 box filter for this block's 4 output rows (s_pad is L2-hot)
    if (tid < 224) {
        int rr = tid / 56, wp = tid - rr * 56;
        const float* sp = s_pad + ((size_t)(b * YP + H0 + rr)) * XP + wp;
        float a = 0.f;
        #pragma unroll
        for (int dy = 0; dy < 3; ++dy)
            #pragma unroll
            for (int dx = 0; dx < 3; ++dx)
                a += sp[dy * XP + dx];
        c2s[tid] = a;
    }

    // ---- stage B once: 2 cc x 6 input rows x 64 x x 64 k = 48 KB ----
    // linear LDS dest; global source chunk pre-swizzled: pe = p ^ ((x>>1)&3)
    const signed char* xb = xqU + (size_t)(b * YP + H0) * XP * CIN_;
    #pragma unroll
    for (int cc = 0; cc < 2; ++cc)
        #pragma unroll
        for (int r_ = 0; r_ < 6; ++r_) {
            int T_ = r_ * 256 + tid;
            int p_ = T_ & 3;
            int x_ = (T_ >> 2) & 63;
            int row_ = T_ >> 8;            // 0..5
            int pe_ = p_ ^ ((x_ >> 1) & 3);
            gload16(xb + (size_t)(row_ * XP + x_) * CIN_ + cc * 64 + pe_ * 16,
                    Bh + cc * 24576 + (r_ * 256 + wv * 64) * 16);
        }

    i32x4 acc[2][4][4];
    #pragma unroll
    for (int tt = 0; tt < 2; ++tt)
        #pragma unroll
        for (int mi = 0; mi < 4; ++mi)
            #pragma unroll
            for (int ni = 0; ni < 4; ++ni)
                acc[tt][mi][ni] = (i32x4){0, 0, 0, 0};

    // per-lane weight stream base and per-lane B x-offsets
    const signed char* aptr = wt + (size_t)(cb * 8192 + mh * 4096) + (size_t)lane * 16;
    int bn_x[4];
    #pragma unroll
    for (int ni = 0; ni < 4; ++ni)
        bn_x[ni] = (ni * 16 + xl) * 64;
    // swizzled chunk offset per dx: (q ^ (((dx+xl)>>1)&3))*16
    int cxo[3];
    #pragma unroll
    for (int d = 0; d < 3; ++d)
        cxo[d] = (q ^ (((d + xl) >> 1) & 3)) * 16;

    i32x4 af[2][4], bf0[4], bf1[4];

    #define LDA(bufv, iv)                                                      \
        {                                                                      \
            _Pragma("unroll")                                                  \
            for (int mi_ = 0; mi_ < 4; ++mi_)                                  \
                af[bufv][mi_] = *(const i32x4*)(aptr + (iv) * 16384 + mi_ * 1024); \
        }
    // tile t reads input rows t*2 + rn + dy (0..5)
    #define LDB(dstv, tv, iv)                                                  \
        {                                                                      \
            const int cc_ = ((iv) >= 9) ? 1 : 0;                               \
            const int g_ = (iv) - cc_ * 9;                                     \
            const int dy_ = g_ / 3, dx_ = g_ - dy_ * 3;                        \
            const int off_ = cc_ * 24576 + ((tv) * 2 * 4096) + dy_ * 4096      \
                             + dx_ * 64 + cxo[dx_];                            \
            const int roff_ = rn * 4096;                                       \
            _Pragma("unroll")                                                  \
            for (int ni_ = 0; ni_ < 4; ++ni_)                                  \
                dstv[ni_] = *(const i32x4*)(Bh + off_ + roff_ + bn_x[ni_]);    \
        }

    LDA(0, 0)                 // global->reg, overlaps the staging drain
    __syncthreads();          // B + c2s ready (vmcnt drained once)

    // D = pixels x weights: col(xl)=cout, row(q*4+j)=x -> contiguous-w regs
    #pragma unroll
    for (int i = 0; i < 18; ++i) {
        const int cur = i & 1, nxt = cur ^ 1;
        if (i < 17) {
            LDA(nxt, i + 1)
        }
        LDB(bf0, 0, i)
        LDB(bf1, 1, i)
        #pragma unroll
        for (int mi = 0; mi < 4; ++mi)
            #pragma unroll
            for (int ni = 0; ni < 4; ++ni)
                acc[0][mi][ni] = __builtin_amdgcn_mfma_i32_16x16x64_i8(
                    bf0[ni], af[cur][mi], acc[0][mi][ni], 0, 0, 0);
        #pragma unroll
        for (int mi = 0; mi < 4; ++mi)
            #pragma unroll
            for (int ni = 0; ni < 4; ++ni)
                acc[1][mi][ni] = __builtin_amdgcn_mfma_i32_16x16x64_i8(
                    bf1[ni], af[cur][mi], acc[1][mi][ni], 0, 0, 0);
    }

    #undef LDA
    #undef LDB

    // Epilogue: c1 = 2*acc + 256*Wsum; out = (gw*c1 + wzp*c2)*fps + bias
    // acc[t][mi][ni][j]: cout = cb*128+mh*64+mi*16+xl, w = ni*16+q*4+j,
    // row = H0 + t*2 + rn -> f4 bias loads + f4 stores, all full-line.
    float gw = p_gw[0];
    #pragma unroll
    for (int tt = 0; tt < 2; ++tt) {
        int hrow = H0 + tt * 2 + rn;
        #pragma unroll
        for (int mi = 0; mi < 4; ++mi) {
            int cout = cb * 128 + mh * 64 + mi * 16 + xl;
            float wz = wzp[cout], fs = fps[cout];
            float base_c = 256.0f * Wsum[cout];
            const float* brow = bias + ((size_t)cout * H_ + hrow) * W_;
            float* orow = out + (((size_t)b * COUT_ + cout) * H_ + hrow) * W_;
            #pragma unroll
            for (int ni = 0; ni < 4; ++ni) {
                int w4 = ni * 16 + q * 4;
                if (w4 < W_) {              // 56 = 14*4: chunk-uniform predicate
                    f4 bi  = *(const f4*)(brow + w4);
                    f4 c2v = *(const f4*)(c2s + (tt * 2 + rn) * 56 + w4);
                    f4 o;
                    #pragma unroll
                    for (int j = 0; j < 4; ++j) {
                        float c1 = 2.0f * (float)acc[tt][mi][ni][j] + base_c;
                        o[j] = (gw * c1 + wz * c2v[j]) * fs + bi[j];
                    }
                    *(f4*)(orow + w4) = o;
                }
            }
        }
    }
}

// ---------------------------------------------------------------------------
extern "C" void kernel_launch(void* const* d_in, const int* in_sizes, int n_in,
                              void* d_out, int out_size, void* d_ws, size_t ws_size,
                              hipStream_t stream)
{
    const float* x     = (const float*)d_in[0];
    const float* wht   = (const float*)d_in[1];
    const float* act_s = (const float*)d_in[2];
    const float* act_q = (const float*)d_in[3];
    const float* azp   = (const float*)d_in[4];
    const float* wzp   = (const float*)d_in[5];
    const float* fps   = (const float*)d_in[6];
    const float* bias  = (const float*)d_in[7];
    const float* ga    = (const float*)d_in[8];
    const float* gw    = (const float*)d_in[9];
    float* out = (float*)d_out;

    char* ws = (char*)d_ws;
    // workspace (16B-aligned offsets):
    //   xqU  : 16*58*64*128 i8 = 7,602,176 B
    //   wt   : 294,912 B
    //   s_pad: 59,392 fp32     =   237,568 B
    //   Wsum : 256 fp32        =     1,024 B      (total ~8.1 MB)
    signed char* xqU  = (signed char*)(ws);
    signed char* wt   = (signed char*)(ws + 7602176);
    float*       spad = (float*)(ws + 7602176 + 294912);
    float*       Wsum = (float*)(ws + 7602176 + 294912 + 237568);

    k_prep<<<dim3(1232), dim3(256), 0, stream>>>(
        x, wht, act_s, act_q, azp, ga, xqU, wt, spad, Wsum);
    k_gemm<<<dim3(448), dim3(256), 0, stream>>>(
        xqU, wt, spad, Wsum, wzp, fps, bias, gw, out);
}

// Round 10
// 128.431 us; speedup vs baseline: 1.0458x; 1.0458x over previous
//
#include <hip/hip_runtime.h>

#define B_    16
#define CIN_  128
#define COUT_ 256
#define H_    56
#define W_    56
#define YP    58
#define XP    64

typedef int   i32x4 __attribute__((ext_vector_type(4)));
typedef float f4    __attribute__((ext_vector_type(4)));

// async global->LDS, 16B per lane; LDS dest wave-uniform base, lane l lands
// at base + l*16.
__device__ __forceinline__ void gload16(const void* g, void* l) {
    __builtin_amdgcn_global_load_lds(
        (const __attribute__((address_space(1))) unsigned int*)g,
        (__attribute__((address_space(3))) unsigned int*)l,
        16, 0, 0);
}

// ---------------------------------------------------------------------------
// Fused prep kernel, block-range partitioned:
//   [0,928)      : quantize x -> xqU i8 (u = xq/2-128, pad = -128) + s_pad
//   [928,1216)   : pack weights -> i8 frag-stream [i(18)][cb(2)][mh(2)][mi(4)][lane(64)][16]
//   [1216,1232)  : Wsum[cout] = sum over cin,ky,kx of weight
__global__ __launch_bounds__(256) void k_prep(
    const float* __restrict__ x, const float* __restrict__ w,
    const float* __restrict__ p_act_s, const float* __restrict__ p_act_q,
    const float* __restrict__ p_azp,  const float* __restrict__ p_guard_a,
    signed char* __restrict__ xqU, signed char* __restrict__ wt,
    float* __restrict__ s_pad, float* __restrict__ Wsum)
{
    int t = threadIdx.x;
    int blk = blockIdx.x;

    if (blk < 928) {
        // ---- quantize one (b, padded-y) row ----
        int b = blk / YP, y = blk - b * YP;
        __shared__ signed char shq[W_ * 144];   // [w][cin], stride 144 (16-mult)
        signed char* orow = xqU + (size_t)blk * XP * CIN_;

        if (y == 0 || y == YP - 1) {
            i32x4 pv = {(int)0x80808080, (int)0x80808080,
                        (int)0x80808080, (int)0x80808080};
            *(i32x4*)(orow + t * 32)      = pv;
            *(i32x4*)(orow + t * 32 + 16) = pv;
            if (t < XP) s_pad[(size_t)blk * XP + t] = 0.0f;
            return;
        }
        int h = y - 1;
        float act_s = p_act_s[0], act_q = p_act_q[0];
        float azp = p_azp[0], ga = p_guard_a[0];
        float zp = azp * act_s / ga;
        float hi = zp + act_q - act_s;
        float inv_s = 1.0f / act_s;            // act_s = 2^-4: exact

        // vectorized: 1792 float4s (56 = 14*4 exact), 16B-aligned rows
        for (int i = 0; i < 7; ++i) {
            int e = i * 256 + t;               // < 1792
            int cin = e / 14;
            int w4 = (e - cin * 14) * 4;
            f4 v = *(const f4*)(x + (((size_t)b * CIN_ + cin) * H_ + h) * W_ + w4);
            #pragma unroll
            for (int j = 0; j < 4; ++j) {
                float vv = fminf(fmaxf(v[j], zp), hi);
                float r = rintf((vv - zp) * inv_s);        // [0,255] integer
                float uq = rintf(ga * r * 0.5f) - 128.0f;  // = r-128 (ga==2)
                shq[(w4 + j) * 144 + cin] = (signed char)(int)uq;
            }
        }
        __syncthreads();
        // write padded row (16B stores, cin contiguous) + channel-sum
        #pragma unroll
        for (int i = 0; i < 2; ++i) {
            int T = i * 256 + t;               // < 512
            int xx = T >> 3;                   // 0..63
            int c16 = T & 7;
            union { i32x4 v; signed char c[16]; } u;
            if (xx >= 1 && xx <= W_) {
                u.v = *(const i32x4*)(shq + (xx - 1) * 144 + c16 * 16);
            } else {
                u.v = (i32x4){(int)0x80808080, (int)0x80808080,
                              (int)0x80808080, (int)0x80808080};
            }
            *(i32x4*)(orow + (size_t)xx * CIN_ + c16 * 16) = u.v;
            int sum = 0;
            #pragma unroll
            for (int j = 0; j < 16; ++j) sum += (int)u.c[j];
            sum += __shfl_xor(sum, 1);
            sum += __shfl_xor(sum, 2);
            sum += __shfl_xor(sum, 4);
            // sum(xq) = 2*sum(u) + 256*128; pads give exactly 0
            if (c16 == 0)
                s_pad[(size_t)blk * XP + xx] = (float)(2 * sum + 32768);
        }
        return;
    }

    if (blk < 1216) {
        // ---- weight pack into MFMA fragment stream ----
        int o = ((blk - 928) * 256 + t) * 4;   // < 294912
        int i_  = o >> 14;                     // 0..17  (= cc*9 + g)
        int cc  = (i_ >= 9) ? 1 : 0;
        int g   = i_ - cc * 9;
        int cbp = (o >> 13) & 1;
        int mh  = (o >> 12) & 1;
        int mi  = (o >> 10) & 3;
        int ln  = (o >> 4) & 63;
        int cout = cbp * 128 + mh * 64 + mi * 16 + (ln & 15);
        int cin0 = cc * 64 + (ln >> 4) * 16 + (o & 15);
        int dy = g / 3, dx = g - dy * 3;
        const float* src = w + (size_t)cout * 1152 + cin0 * 9 + dy * 3 + dx;
        union { int v; signed char c[4]; } pk;
        #pragma unroll
        for (int j = 0; j < 4; ++j)
            pk.c[j] = (signed char)(int)src[j * 9];
        *(int*)(wt + o) = pk.v;
        return;
    }

    {
        // ---- Wsum: 16 couts per block, 16 lanes per cout ----
        int bw = blk - 1216;
        int cout = bw * 16 + (t >> 4);
        int part = t & 15;
        const float* base = w + (size_t)cout * 1152 + part * 72;
        float s = 0.f;
        for (int j = 0; j < 72; ++j) s += base[j];
        s += __shfl_xor(s, 1);
        s += __shfl_xor(s, 2);
        s += __shfl_xor(s, 4);
        s += __shfl_xor(s, 8);
        if (part == 0) Wsum[cout] = s;
        return;
    }
}

// ---------------------------------------------------------------------------
// i8 implicit-GEMM, TWO pixel tiles per block sharing the A (weight) stream:
//   block = 128 cout (cb) x 4 output rows (two 2-row tiles), grid 448.
//   Weights are tile-invariant -> each af fragment feeds 32 MFMAs (2 tiles)
//   instead of 16: doubles compute per A-fetch & per-wave arithmetic density.
//   B: 6 shared input rows (halo row reused) x 2cc staged ONCE (48 KB, XOR
//   swizzle chunk^=(x>>1)&3 -> conflict-free, r6-verified). One barrier.
//   A: L2-hot pre-packed frag stream, global->reg, depth-1 double buffer.
//   Transposed-D epilogue (f4 bias/store), r5-verified.
//   [r8=130.8us best; r9's 1-block/CU pad regressed to 134.3 -> reverted]
__global__ __launch_bounds__(256, 2) void k_gemm(
    const signed char* __restrict__ xqU,  // [B][58][64][128] i8
    const signed char* __restrict__ wt,   // [18][2][2][4][64][16] i8
    const float* __restrict__ s_pad,      // [B*58][64]
    const float* __restrict__ Wsum,       // [256]
    const float* __restrict__ wzp,        // [256]
    const float* __restrict__ fps,        // [256]
    const float* __restrict__ bias,       // [256][56][56]
    const float* __restrict__ p_gw,       // guard_w
    float* __restrict__ out)              // [B][256][56][56]
{
    // [cc(2)][row(6)][x(64)][chunk(4)x16B] + 128 B guard
    __shared__ __align__(16) signed char Bh[2 * 6 * 4096 + 128];
    __shared__ __align__(16) float c2s[4 * 56];

    int tid = threadIdx.x;
    int wv = tid >> 6, lane = tid & 63;
    int xl = lane & 15, q = lane >> 4;
    // XCD-bijective: 448 = 8*56; each XCD gets 56 consecutive u
    // (28 pixel groups x 2 cb, cb pairs adjacent in time).
    int bid = blockIdx.x;
    int u = (bid & 7) * 56 + (bid >> 3);
    int cb = u & 1;
    int g4 = u >> 1;                       // 0..223
    int b = g4 / 14, hp4 = g4 - b * 14;
    int H0 = hp4 * 4;                      // first of 4 output rows
    int mh = wv >> 1;                      // cout half within cb (0/1)
    int rn = wv & 1;                       // row within tile (0/1)

    // c2 box filter for this block's 4 output rows (s_pad is L2-hot)
    if (tid < 224) {
        int rr = tid / 56, wp = tid - rr * 56;
        const float* sp = s_pad + ((size_t)(b * YP + H0 + rr)) * XP + wp;
        float a = 0.f;
        #pragma unroll
        for (int dy = 0; dy < 3; ++dy)
            #pragma unroll
            for (int dx = 0; dx < 3; ++dx)
                a += sp[dy * XP + dx];
        c2s[tid] = a;
    }

    // ---- stage B once: 2 cc x 6 input rows x 64 x x 64 k = 48 KB ----
    // linear LDS dest; global source chunk pre-swizzled: pe = p ^ ((x>>1)&3)
    const signed char* xb = xqU + (size_t)(b * YP + H0) * XP * CIN_;
    #pragma unroll
    for (int cc = 0; cc < 2; ++cc)
        #pragma unroll
        for (int r_ = 0; r_ < 6; ++r_) {
            int T_ = r_ * 256 + tid;
            int p_ = T_ & 3;
            int x_ = (T_ >> 2) & 63;
            int row_ = T_ >> 8;            // 0..5
            int pe_ = p_ ^ ((x_ >> 1) & 3);
            gload16(xb + (size_t)(row_ * XP + x_) * CIN_ + cc * 64 + pe_ * 16,
                    Bh + cc * 24576 + (r_ * 256 + wv * 64) * 16);
        }

    i32x4 acc[2][4][4];
    #pragma unroll
    for (int tt = 0; tt < 2; ++tt)
        #pragma unroll
        for (int mi = 0; mi < 4; ++mi)
            #pragma unroll
            for (int ni = 0; ni < 4; ++ni)
                acc[tt][mi][ni] = (i32x4){0, 0, 0, 0};

    // per-lane weight stream base and per-lane B x-offsets
    const signed char* aptr = wt + (size_t)(cb * 8192 + mh * 4096) + (size_t)lane * 16;
    int bn_x[4];
    #pragma unroll
    for (int ni = 0; ni < 4; ++ni)
        bn_x[ni] = (ni * 16 + xl) * 64;
    // swizzled chunk offset per dx: (q ^ (((dx+xl)>>1)&3))*16
    int cxo[3];
    #pragma unroll
    for (int d = 0; d < 3; ++d)
        cxo[d] = (q ^ (((d + xl) >> 1) & 3)) * 16;

    i32x4 af[2][4], bf0[4], bf1[4];

    #define LDA(bufv, iv)                                                      \
        {                                                                      \
            _Pragma("unroll")                                                  \
            for (int mi_ = 0; mi_ < 4; ++mi_)                                  \
                af[bufv][mi_] = *(const i32x4*)(aptr + (iv) * 16384 + mi_ * 1024); \
        }
    // tile t reads input rows t*2 + rn + dy (0..5)
    #define LDB(dstv, tv, iv)                                                  \
        {                                                                      \
            const int cc_ = ((iv) >= 9) ? 1 : 0;                               \
            const int g_ = (iv) - cc_ * 9;                                     \
            const int dy_ = g_ / 3, dx_ = g_ - dy_ * 3;                        \
            const int off_ = cc_ * 24576 + ((tv) * 2 * 4096) + dy_ * 4096      \
                             + dx_ * 64 + cxo[dx_];                            \
            const int roff_ = rn * 4096;                                       \
            _Pragma("unroll")                                                  \
            for (int ni_ = 0; ni_ < 4; ++ni_)                                  \
                dstv[ni_] = *(const i32x4*)(Bh + off_ + roff_ + bn_x[ni_]);    \
        }

    LDA(0, 0)                 // global->reg, overlaps the staging drain
    __syncthreads();          // B + c2s ready (vmcnt drained once)

    // D = pixels x weights: col(xl)=cout, row(q*4+j)=x -> contiguous-w regs
    #pragma unroll
    for (int i = 0; i < 18; ++i) {
        const int cur = i & 1, nxt = cur ^ 1;
        if (i < 17) {
            LDA(nxt, i + 1)
        }
        LDB(bf0, 0, i)
        LDB(bf1, 1, i)
        #pragma unroll
        for (int mi = 0; mi < 4; ++mi)
            #pragma unroll
            for (int ni = 0; ni < 4; ++ni)
                acc[0][mi][ni] = __builtin_amdgcn_mfma_i32_16x16x64_i8(
                    bf0[ni], af[cur][mi], acc[0][mi][ni], 0, 0, 0);
        #pragma unroll
        for (int mi = 0; mi < 4; ++mi)
            #pragma unroll
            for (int ni = 0; ni < 4; ++ni)
                acc[1][mi][ni] = __builtin_amdgcn_mfma_i32_16x16x64_i8(
                    bf1[ni], af[cur][mi], acc[1][mi][ni], 0, 0, 0);
    }

    #undef LDA
    #undef LDB

    // Epilogue: c1 = 2*acc + 256*Wsum; out = (gw*c1 + wzp*c2)*fps + bias
    // acc[t][mi][ni][j]: cout = cb*128+mh*64+mi*16+xl, w = ni*16+q*4+j,
    // row = H0 + t*2 + rn -> f4 bias loads + f4 stores, all full-line.
    float gw = p_gw[0];
    #pragma unroll
    for (int tt = 0; tt < 2; ++tt) {
        int hrow = H0 + tt * 2 + rn;
        #pragma unroll
        for (int mi = 0; mi < 4; ++mi) {
            int cout = cb * 128 + mh * 64 + mi * 16 + xl;
            float wz = wzp[cout], fs = fps[cout];
            float base_c = 256.0f * Wsum[cout];
            const float* brow = bias + ((size_t)cout * H_ + hrow) * W_;
            float* orow = out + (((size_t)b * COUT_ + cout) * H_ + hrow) * W_;
            #pragma unroll
            for (int ni = 0; ni < 4; ++ni) {
                int w4 = ni * 16 + q * 4;
                if (w4 < W_) {              // 56 = 14*4: chunk-uniform predicate
                    f4 bi  = *(const f4*)(brow + w4);
                    f4 c2v = *(const f4*)(c2s + (tt * 2 + rn) * 56 + w4);
                    f4 o;
                    #pragma unroll
                    for (int j = 0; j < 4; ++j) {
                        float c1 = 2.0f * (float)acc[tt][mi][ni][j] + base_c;
                        o[j] = (gw * c1 + wz * c2v[j]) * fs + bi[j];
                    }
                    *(f4*)(orow + w4) = o;
                }
            }
        }
    }
}

// ---------------------------------------------------------------------------
extern "C" void kernel_launch(void* const* d_in, const int* in_sizes, int n_in,
                              void* d_out, int out_size, void* d_ws, size_t ws_size,
                              hipStream_t stream)
{
    const float* x     = (const float*)d_in[0];
    const float* wht   = (const float*)d_in[1];
    const float* act_s = (const float*)d_in[2];
    const float* act_q = (const float*)d_in[3];
    const float* azp   = (const float*)d_in[4];
    const float* wzp   = (const float*)d_in[5];
    const float* fps   = (const float*)d_in[6];
    const float* bias  = (const float*)d_in[7];
    const float* ga    = (const float*)d_in[8];
    const float* gw    = (const float*)d_in[9];
    float* out = (float*)d_out;

    char* ws = (char*)d_ws;
    // workspace (16B-aligned offsets):
    //   xqU  : 16*58*64*128 i8 = 7,602,176 B
    //   wt   : 294,912 B
    //   s_pad: 59,392 fp32     =   237,568 B
    //   Wsum : 256 fp32        =     1,024 B      (total ~8.1 MB)
    signed char* xqU  = (signed char*)(ws);
    signed char* wt   = (signed char*)(ws + 7602176);
    float*       spad = (float*)(ws + 7602176 + 294912);
    float*       Wsum = (float*)(ws + 7602176 + 294912 + 237568);

    k_prep<<<dim3(1232), dim3(256), 0, stream>>>(
        x, wht, act_s, act_q, azp, ga, xqU, wt, spad, Wsum);
    k_gemm<<<dim3(448), dim3(256), 0, stream>>>(
        xqU, wt, spad, Wsum, wzp, fps, bias, gw, out);
}